// Round 6
// baseline (923.614 us; speedup 1.0000x reference)
//
#include <hip/hip_runtime.h>
#include <hip/hip_bf16.h>

#define B_TOK 2048
#define DDIM 1024
#define FDIM 4096
#define NE 16
#define NG 2
#define BD ((long)B_TOK * DDIM)

typedef unsigned short u16;
typedef __attribute__((ext_vector_type(8))) short bf16x8;   // 8 bf16 (4 VGPRs)
typedef __attribute__((ext_vector_type(4))) float f32x4;

// ---------- helpers ----------
__device__ inline u16 f2bf(float x) {           // RNE f32 -> bf16 bits
  union { float f; unsigned u; } v; v.f = x;
  return (u16)((v.u + 0x7fffu + ((v.u >> 16) & 1u)) >> 16);
}
__device__ inline float bfround(float x) {      // f32 -> bf16 -> f32 (matches astype(bf16))
  union { float f; unsigned u; } v; v.f = x;
  v.u = ((v.u + 0x7fffu + ((v.u >> 16) & 1u)) >> 16) << 16;
  return v.f;
}
// Abramowitz-Stegun 7.1.26 erf, |eps| <= 1.5e-7
__device__ inline float fast_erf(float x) {
  float ax = fabsf(x);
  float t = __builtin_amdgcn_rcpf(1.0f + 0.3275911f * ax);
  float poly = t * (0.254829592f + t * (-0.284496736f + t * (1.421413741f +
               t * (-1.453152027f + t * 1.061405429f))));
  float r = 1.0f - poly * __expf(-ax * ax);
  return copysignf(r, x);
}
__device__ inline float gelu_exact(float x) {
  return 0.5f * x * (1.0f + fast_erf(x * 0.70710678118654752440f));
}
__device__ inline void gload16(const void* g, void* l) {
  // LDS dest is wave-uniform base; HW adds lane*16 (guide m104/m108).
  __builtin_amdgcn_global_load_lds((const __attribute__((address_space(1))) void*)g,
                                   (__attribute__((address_space(3))) void*)l, 16, 0, 0);
}
__device__ inline float waveSum(float v) {
  v += __shfl_down(v, 32); v += __shfl_down(v, 16); v += __shfl_down(v, 8);
  v += __shfl_down(v, 4);  v += __shfl_down(v, 2);  v += __shfl_down(v, 1);
  return v;
}

// ---------- gating + loss partials ----------
__global__ __launch_bounds__(256) void gating_kernel(
    const float* __restrict__ logits, const int* __restrict__ masks,
    float* __restrict__ gates, float* __restrict__ loss)
{
  const int b = blockIdx.x * 256 + threadIdx.x;       // grid 8 x 256 == 2048
  const int lane = threadIdx.x & 63;
  const float* lr = logits + (long)b * NE;
  const int*   mr = masks  + (long)b * NE;
  float raw[NE]; int mk[NE];
  float mx = -1e30f;
#pragma unroll
  for (int e = 0; e < NE; ++e) { raw[e] = lr[e]; mx = fmaxf(mx, raw[e]); }
  float s = 0.f;
#pragma unroll
  for (int e = 0; e < NE; ++e) { raw[e] = expf(raw[e] - mx); s += raw[e]; }
  float inv = 1.0f / s;
#pragma unroll
  for (int e = 0; e < NE; ++e) raw[e] *= inv;
  float gs = 0.f;
#pragma unroll
  for (int e = 0; e < NE; ++e) { mk[e] = (mr[e] == 1); gs += mk[e] ? raw[e] : 0.f; }
  float ginv = 1.0f / (gs + 1e-9f);
  float* gr = gates + (long)b * NE;
#pragma unroll
  for (int e = 0; e < NE; ++e) gr[e] = (mk[e] ? raw[e] : 0.f) * ginv;
#pragma unroll
  for (int e = 0; e < NE; ++e) {
    float cs = waveSum(raw[e]);
    float cc = waveSum(mk[e] ? 1.f : 0.f);
    if (lane == 0) { atomicAdd(&loss[e], cs); atomicAdd(&loss[NE + e], cc); }
  }
  float t = waveSum(gs);
  if (lane == 0) atomicAdd(&loss[32], t);
}

__global__ void finalize_loss(const float* __restrict__ loss, float* __restrict__ out2) {
  if (threadIdx.x == 0) {
    float aug = 0.f;
    for (int e = 0; e < NE; ++e)
      aug += (loss[e] / (float)B_TOK) * (loss[NE + e] / (float)B_TOK);
    aug *= (1.0f / NE);
    float s = loss[32] / (float)B_TOK;
    out2[0] = aug;
    out2[1] = (1.f - s) * (1.f - s);
  }
}

// ---------- deterministic per-expert token compaction + inverse map ----------
__global__ __launch_bounds__(256) void compact_kernel(
    const int* __restrict__ masks, int* __restrict__ tok,
    int* __restrict__ pos, int* __restrict__ cnts)
{
  const int e = blockIdx.x, tid = threadIdx.x;
  const int lane = tid & 63, wave = tid >> 6;
  __shared__ int wcnt[4];
  __shared__ int runbase;
  if (tid == 0) runbase = 0;
  __syncthreads();
  for (int b0 = 0; b0 < B_TOK; b0 += 256) {
    int b = b0 + tid;
    int m = (masks[(long)b * NE + e] == 1);
    unsigned long long bal = __ballot(m);
    int pre = __popcll(bal & ((1ull << lane) - 1ull));
    if (lane == 0) wcnt[wave] = __popcll(bal);
    __syncthreads();
    int base = runbase;
    for (int w = 0; w < wave; ++w) base += wcnt[w];
    if (m) {
      int p = base + pre;
      tok[(e << 11) + p] = b;
      pos[(long)b * NE + e] = p;
    } else {
      pos[(long)b * NE + e] = -1;
    }
    __syncthreads();
    if (tid == 0) runbase += wcnt[0] + wcnt[1] + wcnt[2] + wcnt[3];
    __syncthreads();
  }
  const int cnt = runbase;
  const int cnt_pad = (cnt + 255) & ~255;              // 256-tile padding
  for (int i = cnt + tid; i < cnt_pad; i += 256)
    tok[(e << 11) + i] = 0;          // safe row; pad output rows never read
  if (tid == 0) { cnts[e] = cnt; cnts[NE + e] = cnt_pad; }
}

// ---------- x f32 -> bf16 ----------
__global__ __launch_bounds__(256) void cvt_x_kernel(const float* __restrict__ x, u16* __restrict__ xb) {
  long i = ((long)blockIdx.x * 256 + threadIdx.x) * 4;
  float4 v = *(const float4*)&x[i];
  ushort4 o; o.x = f2bf(v.x); o.y = f2bf(v.y); o.z = f2bf(v.z); o.w = f2bf(v.w);
  *(ushort4*)&xb[i] = o;
}

// ---------- moe bias: moe_bias[b,d] = sum_e gates[b,e]*eb[e,d] ----------
__global__ __launch_bounds__(256) void bias_init_kernel(
    const float* __restrict__ gates, const float* __restrict__ eb,
    float* __restrict__ moe_bias)
{
  long i = (long)blockIdx.x * 256 + threadIdx.x;       // grid 8192 -> B*D
  int b = (int)(i >> 10), d = (int)(i & 1023);
  const float* gr = gates + (long)b * NE;
  float s = 0.f;
#pragma unroll
  for (int e = 0; e < NE; ++e) s += gr[e] * eb[e * DDIM + d];
  moe_bias[i] = s;
}

// ---------- transpose + f32->bf16: src [R,C] -> dst [C,R] ----------
__global__ __launch_bounds__(256) void transpose_cvt(
    const float* __restrict__ src, u16* __restrict__ dst,
    int R, int C, long sZ, long dZ)
{
  __shared__ float t[64][65];
  const float* s = src + (long)blockIdx.z * sZ;
  u16* d = dst + (long)blockIdx.z * dZ;
  const int c0 = blockIdx.x * 64, r0 = blockIdx.y * 64;
  const int tid = threadIdx.x;
#pragma unroll
  for (int it = 0; it < 4; ++it) {
    int idx = tid + it * 256;
    int r = idx >> 4, cq = (idx & 15) * 4;
    float4 v = *(const float4*)&s[(long)(r0 + r) * C + c0 + cq];
    t[r][cq] = v.x; t[r][cq + 1] = v.y; t[r][cq + 2] = v.z; t[r][cq + 3] = v.w;
  }
  __syncthreads();
#pragma unroll
  for (int it = 0; it < 4; ++it) {
    int idx = tid + it * 256;
    int c = idx >> 4, rq = (idx & 15) * 4;
    ushort4 o;
    o.x = f2bf(t[rq][c]); o.y = f2bf(t[rq+1][c]); o.z = f2bf(t[rq+2][c]); o.w = f2bf(t[rq+3][c]);
    *(ushort4*)&d[(long)(c0 + c) * R + r0 + rq] = o;
  }
}

// ---------- 256-wide MFMA GEMM, BK=64, 8 waves, counted-vmcnt ring, swizzled LDS ----------
// PROJ 0 (in-proj):  BM=256,BN=256, K=1024, 2 bufs (128KB), depth-1 prefetch.
//   z<16: A rows gathered via tok (xb); z>=16: identity rows (general). Out: Hb[z]=bf16(gelu).
// PROJ 1 (out-proj): BM=256,BN=128, K=4096, 3 bufs (144KB), depth-2 prefetch.
//   A = Hb[z]; out: z<16 -> Eout[z] (f32, write-only); z>=16 -> genp[z-16].
// LDS swizzle (T2, rule #21 both-sides): row's 64-elem k-window stored XOR'd by
// ((row&7)*8 elems); staging pre-swizzles the per-lane GLOBAL source (LDS dest
// stays linear for global_load_lds), reads apply the same involution.
template<int PROJ>
__global__ __launch_bounds__(512, 2) void gemm256(
    const u16* __restrict__ A, int lda, long aZ,
    const u16* __restrict__ Bm, int ldb,
    int klen,
    u16* __restrict__ H,
    float* __restrict__ Eout, float* __restrict__ genp,
    const int* __restrict__ tok, const int* __restrict__ cnts)
{
  constexpr int BN    = PROJ ? 128 : 256;
  constexpr int NBS   = BN / 64;           // B staging steps (8KB each)
  constexpr int DEPTH = PROJ ? 2 : 1;
  constexpr int NBUF  = DEPTH + 1;
  constexpr int WN    = BN / 64;           // waves along N
  constexpr int MI    = PROJ ? 4 : 8;      // m-frags per wave
  __shared__ u16 lds[NBUF][16384 + BN * 64];

  // raster: m (by) fastest within (z, n) for B-panel L2 reuse; bijective XCD swizzle
  int lin = ((int)blockIdx.z * gridDim.x + blockIdx.x) * gridDim.y + blockIdx.y;
  const int T = gridDim.x * gridDim.y * gridDim.z;     // divisible by 8 by construction
  lin = (lin & 7) * (T >> 3) + (lin >> 3);
  const int by = lin % gridDim.y;  int tmp = lin / gridDim.y;
  const int bx = tmp % gridDim.x;  const int z = tmp / gridDim.x;

  const int m0 = by * 256, n0 = bx * BN;
  if (z < NE && m0 >= cnts[NE + z]) return;            // routed: beyond padded count

  const int tid = threadIdx.x, lane = tid & 63, wave = tid >> 6;
  const int wr = wave / WN, wc = wave % WN;
  const int srow = wave * 8 + (lane >> 3);             // staging row within 64-row step
  const int swz  = ((lane & 7) * 8) ^ ((lane >> 3) * 8);  // pre-swizzled source k-offset

  const u16* aSrc[4];
  const u16* bSrc[NBS];
  const u16* Bz = Bm + (long)z * ((long)DDIM * FDIM);
#pragma unroll
  for (int s = 0; s < 4; ++s) {
    int r = m0 + s * 64 + srow;
    if (PROJ == 0 && z < NE) r = tok[(z << 11) + r];   // gather (per-lane global ok)
    const u16* Abase = (PROJ == 0) ? A : A + (long)z * aZ;
    aSrc[s] = Abase + (long)r * lda + swz;
  }
#pragma unroll
  for (int s = 0; s < NBS; ++s)
    bSrc[s] = Bz + (long)(n0 + s * 64 + srow) * ldb + swz;

  auto STAGE = [&](int buf, int kk) {
    u16* la = &lds[buf][0];
    u16* lb = &lds[buf][16384];
#pragma unroll
    for (int s = 0; s < 4; ++s)
      gload16(aSrc[s] + kk, la + s * 4096 + wave * 512);
#pragma unroll
    for (int s = 0; s < NBS; ++s)
      gload16(bSrc[s] + kk, lb + s * 4096 + wave * 512);
  };

  f32x4 zero = {0.f, 0.f, 0.f, 0.f};
  f32x4 acc[MI][4];
#pragma unroll
  for (int mi = 0; mi < MI; ++mi)
#pragma unroll
    for (int ni = 0; ni < 4; ++ni) acc[mi][ni] = zero;

  auto COMPUTE = [&](int buf) {
    const u16* la = &lds[buf][0];
    const u16* lb = &lds[buf][16384];
#pragma unroll
    for (int k2 = 0; k2 < 2; ++k2) {
      const int fk = (lane >> 4) * 8 + k2 * 32;
      bf16x8 bv[4];
#pragma unroll
      for (int ni = 0; ni < 4; ++ni) {
        int br = wc * 64 + ni * 16 + (lane & 15);
        bv[ni] = *(const bf16x8*)(lb + br * 64 + (fk ^ ((br & 7) << 3)));
      }
#pragma unroll
      for (int mi = 0; mi < MI; ++mi) {
        int ar = wr * (MI * 16) + mi * 16 + (lane & 15);
        bf16x8 av = *(const bf16x8*)(la + ar * 64 + (fk ^ ((ar & 7) << 3)));
#pragma unroll
        for (int ni = 0; ni < 4; ++ni)
          acc[mi][ni] = __builtin_amdgcn_mfma_f32_16x16x32_bf16(av, bv[ni], acc[mi][ni], 0, 0, 0);
      }
    }
  };

  // counted-vmcnt ring pipeline: stage DEPTH tiles ahead; in-loop waits leave
  // DEPTH*loads outstanding (never 0 until the tail).
  const int NT = klen >> 6;
  STAGE(0, 0);
  if (DEPTH == 2) STAGE(1, 64);
  int cur = 0, stg = DEPTH;
  for (int t = 0; t < NT; ++t) {
    const int ahead = t + DEPTH;
    if (ahead < NT) {
      STAGE(stg, ahead << 6);
      if (PROJ) asm volatile("s_waitcnt vmcnt(12)" ::: "memory");  // 2 tiles x 6 loads
      else      asm volatile("s_waitcnt vmcnt(8)"  ::: "memory");  // 1 tile  x 8 loads
    } else if (PROJ == 1 && t + 1 < NT) {
      asm volatile("s_waitcnt vmcnt(6)" ::: "memory");
    } else {
      asm volatile("s_waitcnt vmcnt(0)" ::: "memory");
    }
    __builtin_amdgcn_s_barrier();
    asm volatile("" ::: "memory");
    COMPUTE(cur);
    asm volatile("" ::: "memory");
    __builtin_amdgcn_s_barrier();
    asm volatile("" ::: "memory");
    cur = (cur + 1 == NBUF) ? 0 : cur + 1;
    stg = (stg + 1 == NBUF) ? 0 : stg + 1;
  }

  // epilogue: C/D map col=lane&15, row=(lane>>4)*4+j  (guide m89/m91)
  const int er = m0 + wr * (MI * 16) + (lane >> 4) * 4;
  const int ec = n0 + wc * 64 + (lane & 15);
  if (PROJ == 0) {
    u16* Hz = H + (long)z * ((long)B_TOK * FDIM);
#pragma unroll
    for (int mi = 0; mi < MI; ++mi)
#pragma unroll
      for (int ni = 0; ni < 4; ++ni) {
        f32x4 v = acc[mi][ni];
        int rb = er + mi * 16, cb = ec + ni * 16;
#pragma unroll
        for (int j = 0; j < 4; ++j)
          Hz[(long)(rb + j) * FDIM + cb] = f2bf(gelu_exact(v[j]));
      }
  } else {
    float* Cz = (z < NE) ? (Eout + (long)z * BD) : (genp + (long)(z - NE) * BD);
#pragma unroll
    for (int mi = 0; mi < MI; ++mi)
#pragma unroll
      for (int ni = 0; ni < 4; ++ni) {
        f32x4 v = acc[mi][ni];
        int rb = er + mi * 16, cb = ec + ni * 16;
#pragma unroll
        for (int j = 0; j < 4; ++j)
          Cz[(long)(rb + j) * DDIM + cb] = v[j];
      }
  }
}

// ---------- combine (gate-weighted gather) + general + residual + LayerNorm ----------
__global__ __launch_bounds__(256) void combine_ln_kernel(
    const float* __restrict__ x, const float* __restrict__ moe_bias,
    const float* __restrict__ Eout, const float* __restrict__ gen_p,
    const float* __restrict__ gb,
    const int* __restrict__ pos, const float* __restrict__ gates,
    const float* __restrict__ gamma, const float* __restrict__ beta,
    float* __restrict__ out)
{
  const int b = blockIdx.x, tid = threadIdx.x;
  const int lane = tid & 63, wave = tid >> 6;
  const long base = (long)b * DDIM;
  __shared__ int posr[NE];
  __shared__ float gr[NE];
  __shared__ float red[4];
  if (tid < NE) { posr[tid] = pos[(long)b * NE + tid]; gr[tid] = gates[(long)b * NE + tid]; }
  __syncthreads();
  float y[4];
  float ls = 0.f;
#pragma unroll
  for (int i = 0; i < 4; ++i) {
    int d = tid + i * 256;
    long idx = base + d;
    float moe = moe_bias[idx];
#pragma unroll
    for (int e = 0; e < NE; ++e) {
      int p = posr[e];                                  // block-uniform -> no divergence
      if (p >= 0) moe += gr[e] * Eout[((long)e * B_TOK + p) * DDIM + d];
    }
    moe = bfround(moe);                                 // matches ref's bf16 cast of moe_out
    float ge = gb[d] + gb[DDIM + d] + gen_p[idx] + gen_p[BD + idx];
    y[i] = moe + ge + x[idx];
    ls += y[i];
  }
  float t = waveSum(ls);
  if (lane == 0) red[wave] = t;
  __syncthreads();
  float mean = (red[0] + red[1] + red[2] + red[3]) * (1.0f / DDIM);
  __syncthreads();
  float vs = 0.f;
#pragma unroll
  for (int i = 0; i < 4; ++i) { float d2 = y[i] - mean; vs += d2 * d2; }
  t = waveSum(vs);
  if (lane == 0) red[wave] = t;
  __syncthreads();
  float var = (red[0] + red[1] + red[2] + red[3]) * (1.0f / DDIM);
  float inv = rsqrtf(var + 1e-5f);
#pragma unroll
  for (int i = 0; i < 4; ++i) {
    int d = tid + i * 256;
    out[base + d] = (y[i] - mean) * inv * gamma[d] + beta[d];
  }
}

// ---------- orchestration ----------
extern "C" void kernel_launch(void* const* d_in, const int* in_sizes, int n_in,
                              void* d_out, int out_size, void* d_ws, size_t ws_size,
                              hipStream_t stream)
{
  const float* x      = (const float*)d_in[0];
  const float* logits = (const float*)d_in[1];
  const int*   masks  = (const int*)d_in[2];
  const float* ew_in  = (const float*)d_in[3];
  const float* ew_out = (const float*)d_in[4];
  const float* eb_out = (const float*)d_in[5];
  const float* gw_in  = (const float*)d_in[6];
  const float* gw_out = (const float*)d_in[7];
  const float* gb_out = (const float*)d_in[8];
  const float* gamma  = (const float*)d_in[9];
  const float* beta   = (const float*)d_in[10];
  float* out = (float*)d_out;

  char* w = (char*)d_ws;
  size_t off = 0;
  auto alloc = [&](size_t bytes) -> void* {
    off = (off + 4095) & ~(size_t)4095;
    void* p = w + off; off += bytes; return p;
  };
  const long DF = (long)DDIM * FDIM;          // 4.19M elems
  const long BF = (long)B_TOK * FDIM;         // 8.39M elems
  const int  NZ = NE + NG;                    // 18 unified expert slots

  float* gates    = (float*)alloc((size_t)B_TOK * NE * 4);
  float* loss     = (float*)alloc(64 * 4);
  int*   tok      = (int*)alloc((size_t)NE * B_TOK * 4);
  int*   pos      = (int*)alloc((size_t)B_TOK * NE * 4);
  int*   cnts     = (int*)alloc(2 * NE * 4);
  u16*   xb       = (u16*)alloc((size_t)BD * 2);
  float* moe_bias = (float*)alloc((size_t)BD * 4);
  float* gen_p    = (float*)alloc((size_t)NG * BD * 4);          // 2 slices (per g)
  float* Eout     = (float*)alloc((size_t)NE * BD * 4);          // per-expert compact f32
  u16*   WinT     = (u16*)alloc((size_t)NZ * DF * 2);            // [F,D] per slot
  u16*   WoutT    = (u16*)alloc((size_t)NZ * DF * 2);            // [D,F] per slot
  u16*   Hb       = (u16*)alloc((size_t)NZ * BF * 2);            // gelu acts per slot

  hipMemsetAsync(loss, 0, 64 * 4, stream);
  gating_kernel<<<8, 256, 0, stream>>>(logits, masks, gates, loss);
  finalize_loss<<<1, 64, 0, stream>>>(loss, out + BD);
  compact_kernel<<<NE, 256, 0, stream>>>(masks, tok, pos, cnts);
  cvt_x_kernel<<<2048, 256, 0, stream>>>(x, xb);
  bias_init_kernel<<<8192, 256, 0, stream>>>(gates, eb_out, moe_bias);

  // all weight transposes up front (routed slots 0..15, general 16..17)
  transpose_cvt<<<dim3(FDIM/64, DDIM/64, NE), 256, 0, stream>>>(
      ew_in, WinT, DDIM, FDIM, DF, DF);
  transpose_cvt<<<dim3(FDIM/64, DDIM/64, NG), 256, 0, stream>>>(
      gw_in, WinT + (long)NE * DF, DDIM, FDIM, DF, DF);
  transpose_cvt<<<dim3(DDIM/64, FDIM/64, NE), 256, 0, stream>>>(
      ew_out, WoutT, FDIM, DDIM, DF, DF);
  transpose_cvt<<<dim3(DDIM/64, FDIM/64, NG), 256, 0, stream>>>(
      gw_out, WoutT + (long)NE * DF, FDIM, DDIM, DF, DF);

  // in-proj, all 18 slots: [M,1024] x [4096,1024]^T -> Hb (bf16 gelu)
  gemm256<0><<<dim3(FDIM/256, B_TOK/256, NZ), 512, 0, stream>>>(
      xb, DDIM, 0L, WinT, DDIM, DDIM,
      Hb, nullptr, nullptr, tok, cnts);
  // out-proj, all 18 slots: [M,4096] x [1024,4096]^T -> Eout / gen_p (f32)
  gemm256<1><<<dim3(DDIM/128, B_TOK/256, NZ), 512, 0, stream>>>(
      Hb, FDIM, BF, WoutT, FDIM, FDIM,
      nullptr, Eout, gen_p, nullptr, cnts);

  combine_ln_kernel<<<B_TOK, 256, 0, stream>>>(
      x, moe_bias, Eout, gen_p, gb_out, pos, gates, gamma, beta, out);
}